// Round 1
// baseline (1105.143 us; speedup 1.0000x reference)
//
#include <hip/hip_runtime.h>
#include <cstdint>

using short8  = __attribute__((ext_vector_type(8))) short;
using floatx4 = __attribute__((ext_vector_type(4))) float;

__device__ __forceinline__ unsigned short f2bf(float x){
  union { float f; unsigned u; } v; v.f = x;
  unsigned r = v.u + 0x7fffu + ((v.u >> 16) & 1u);
  return (unsigned short)(r >> 16);
}

__device__ __forceinline__ float eluf(float v){ return v > 0.f ? v : expm1f(v); }

__device__ __forceinline__ void ld_g2l16(const void* g, void* l){
  __builtin_amdgcn_global_load_lds(
      (const __attribute__((address_space(1))) void*)g,
      (__attribute__((address_space(3))) void*)l, 16, 0, 0);
}

// ---------------- weight transpose + bf16 convert: Wt[n*K+k] = W[k*N+n] ----
__global__ void k_tcvt(const float* __restrict__ W, unsigned short* __restrict__ Wt,
                       int K, int Ncols){
  int idx = blockIdx.x * 256 + threadIdx.x;
  if (idx >= K * Ncols) return;
  int n = idx / K, k = idx - n * K;
  Wt[idx] = f2bf(W[(size_t)k * Ncols + n]);
}

// ---------------- maxpool(2) + layernorm(1024) -> bf16 ---------------------
__global__ __launch_bounds__(256) void k_pool_ln(const float* __restrict__ x,
    const float* __restrict__ g, const float* __restrict__ b,
    unsigned short* __restrict__ h0){
  const int i = blockIdx.x, t = threadIdx.x;
  const float4* xr = (const float4*)(x + (size_t)i * 2048);
  float4 va = xr[2 * t], vb = xr[2 * t + 1];
  float v0 = fmaxf(va.x, va.y), v1 = fmaxf(va.z, va.w);
  float v2 = fmaxf(vb.x, vb.y), v3 = fmaxf(vb.z, vb.w);
  float s  = v0 + v1 + v2 + v3;
  float s2 = v0*v0 + v1*v1 + v2*v2 + v3*v3;
  #pragma unroll
  for (int off = 32; off > 0; off >>= 1){
    s  += __shfl_down(s, off);
    s2 += __shfl_down(s2, off);
  }
  __shared__ float ps[4], ps2[4];
  int w = t >> 6;
  if ((t & 63) == 0){ ps[w] = s; ps2[w] = s2; }
  __syncthreads();
  float S  = ps[0] + ps[1] + ps[2] + ps[3];
  float S2 = ps2[0] + ps2[1] + ps2[2] + ps2[3];
  float mu   = S * (1.f / 1024.f);
  float var  = S2 * (1.f / 1024.f) - mu * mu;
  float rstd = rsqrtf(var + 1e-5f);
  float4 g4 = ((const float4*)g)[t];
  float4 b4 = ((const float4*)b)[t];
  ushort4 o;
  o.x = f2bf((v0 - mu) * rstd * g4.x + b4.x);
  o.y = f2bf((v1 - mu) * rstd * g4.y + b4.y);
  o.z = f2bf((v2 - mu) * rstd * g4.z + b4.z);
  o.w = f2bf((v3 - mu) * rstd * g4.w + b4.w);
  *(ushort4*)(h0 + (size_t)i * 1024 + t * 4) = o;
}

// ---------------- main MFMA GEMM: C = elu(A@B + bias), bf16 out ------------
// A: M x K (bf16)   Bt: N x K (bf16, = B^T)   C: M x N (bf16)
// 128x128 tile, BK=64, 4 waves (2x2), XOR-swizzled LDS, global_load_lds x16.
__global__ __launch_bounds__(256) void k_gemm(const unsigned short* __restrict__ A,
    const unsigned short* __restrict__ Bt, const float* __restrict__ bias,
    unsigned short* __restrict__ C, int M, int K, int N){
  __shared__ __align__(16) unsigned short lA[128 * 64];
  __shared__ __align__(16) unsigned short lB[128 * 64];
  const int tid  = threadIdx.x;
  const int lane = tid & 63;
  const int w    = tid >> 6;
  const int wm = w >> 1, wn = w & 1;
  const int m0 = blockIdx.x * 128;
  const int n0 = blockIdx.y * 128;
  const int q = lane >> 4, ml = lane & 15;
  floatx4 acc[4][4] = {};
  const int nKB = K >> 6;
  for (int kb = 0; kb < nKB; ++kb){
    #pragma unroll
    for (int i = 0; i < 4; ++i){
      int cpos = (w * 4 + i) * 64 + lane;
      int row  = cpos >> 3;
      int p    = cpos & 7;
      int cc   = p ^ (row & 7);          // XOR swizzle on 16B chunks
      int ar   = m0 + row; ar = ar < M ? ar : M - 1;
      ld_g2l16(A  + (size_t)ar        * K + (kb * 64 + cc * 8), &lA[(w * 4 + i) * 512]);
      ld_g2l16(Bt + (size_t)(n0 + row) * K + (kb * 64 + cc * 8), &lB[(w * 4 + i) * 512]);
    }
    __syncthreads();
    #pragma unroll
    for (int kk = 0; kk < 2; ++kk){
      short8 af[4], bfr[4];
      #pragma unroll
      for (int mi = 0; mi < 4; ++mi){
        int row = wm * 64 + mi * 16 + ml;
        int p   = (kk * 4 + q) ^ (row & 7);
        af[mi] = *(const short8*)&lA[row * 64 + p * 8];
      }
      #pragma unroll
      for (int ni = 0; ni < 4; ++ni){
        int row = wn * 64 + ni * 16 + ml;
        int p   = (kk * 4 + q) ^ (row & 7);
        bfr[ni] = *(const short8*)&lB[row * 64 + p * 8];
      }
      #pragma unroll
      for (int mi = 0; mi < 4; ++mi)
        #pragma unroll
        for (int ni = 0; ni < 4; ++ni)
          acc[mi][ni] = __builtin_amdgcn_mfma_f32_16x16x32_bf16(af[mi], bfr[ni], acc[mi][ni], 0, 0, 0);
    }
    __syncthreads();
  }
  #pragma unroll
  for (int mi = 0; mi < 4; ++mi){
    #pragma unroll
    for (int ni = 0; ni < 4; ++ni){
      int gc = n0 + wn * 64 + ni * 16 + ml;
      float bv = bias[gc];
      #pragma unroll
      for (int r = 0; r < 4; ++r){
        int gr = m0 + wm * 64 + mi * 16 + q * 4 + r;
        if (gr < M){
          float v = acc[mi][ni][r] + bv;
          v = v > 0.f ? v : expm1f(v);
          C[(size_t)gr * N + gc] = f2bf(v);
        }
      }
    }
  }
}

// ------------- h3 = elu(h2 @ w2 + b2): K=128, N=64, 1 wave per 16 rows -----
__global__ __launch_bounds__(256) void k_h3(const unsigned short* __restrict__ h2,
    const unsigned short* __restrict__ w2t, const float* __restrict__ b2,
    unsigned short* __restrict__ h3, int M){
  int gw = (blockIdx.x * 256 + threadIdx.x) >> 6;
  int lane = threadIdx.x & 63;
  int r0 = gw * 16;
  if (r0 >= M) return;
  int ml = lane & 15, q = lane >> 4;
  int ar = r0 + ml; if (ar >= M) ar = M - 1;
  floatx4 acc[4] = {};
  #pragma unroll
  for (int kk = 0; kk < 4; ++kk){
    short8 a = *(const short8*)&h2[(size_t)ar * 128 + kk * 32 + q * 8];
    #pragma unroll
    for (int ni = 0; ni < 4; ++ni){
      short8 bb = *(const short8*)&w2t[(ni * 16 + ml) * 128 + kk * 32 + q * 8];
      acc[ni] = __builtin_amdgcn_mfma_f32_16x16x32_bf16(a, bb, acc[ni], 0, 0, 0);
    }
  }
  #pragma unroll
  for (int ni = 0; ni < 4; ++ni){
    int gc = ni * 16 + ml;
    float bv = b2[gc];
    #pragma unroll
    for (int r = 0; r < 4; ++r){
      int gr = r0 + q * 4 + r;
      if (gr < M) h3[(size_t)gr * 64 + gc] = f2bf(eluf(acc[ni][r] + bv));
    }
  }
}

// ------------- xs1 = (h3 @ c1w) * dinv; acc1 = xs1 (self-loop init) --------
__global__ __launch_bounds__(256) void k_xs1(const unsigned short* __restrict__ h3,
    const unsigned short* __restrict__ c1wt, const float* __restrict__ dinv,
    float* __restrict__ xs1, float* __restrict__ acc1, int M){
  int gw = (blockIdx.x * 256 + threadIdx.x) >> 6;
  int lane = threadIdx.x & 63;
  int r0 = gw * 16;
  if (r0 >= M) return;
  int ml = lane & 15, q = lane >> 4;
  int ar = r0 + ml; if (ar >= M) ar = M - 1;
  floatx4 acc[2] = {};
  #pragma unroll
  for (int kk = 0; kk < 2; ++kk){
    short8 a = *(const short8*)&h3[(size_t)ar * 64 + kk * 32 + q * 8];
    #pragma unroll
    for (int ni = 0; ni < 2; ++ni){
      short8 bb = *(const short8*)&c1wt[(ni * 16 + ml) * 64 + kk * 32 + q * 8];
      acc[ni] = __builtin_amdgcn_mfma_f32_16x16x32_bf16(a, bb, acc[ni], 0, 0, 0);
    }
  }
  #pragma unroll
  for (int ni = 0; ni < 2; ++ni){
    int gc = ni * 16 + ml;
    #pragma unroll
    for (int r = 0; r < 4; ++r){
      int gr = r0 + q * 4 + r;
      if (gr < M){
        float v = acc[ni][r] * dinv[gr];
        xs1[(size_t)gr * 32 + gc]  = v;
        acc1[(size_t)gr * 32 + gc] = v;
      }
    }
  }
}

// ------------- h4 = elu(dinv*acc1 + c1b); xs2 = (h4@c2w)*dinv; acc2=xs2 ----
__global__ __launch_bounds__(256) void k_fin1(const float* __restrict__ acc1,
    const float* __restrict__ c1b, const unsigned short* __restrict__ c2wt,
    const float* __restrict__ dinv, float* __restrict__ xs2,
    float* __restrict__ acc2, int M){
  int gw = (blockIdx.x * 256 + threadIdx.x) >> 6;
  int lane = threadIdx.x & 63;
  int r0 = gw * 16;
  if (r0 >= M) return;
  int ml = lane & 15, q = lane >> 4;
  int ar = r0 + ml; if (ar >= M) ar = M - 1;
  float dr = dinv[ar];
  short8 a;
  #pragma unroll
  for (int j = 0; j < 8; ++j){
    float v = dr * acc1[(size_t)ar * 32 + q * 8 + j] + c1b[q * 8 + j];
    a[j] = (short)f2bf(eluf(v));
  }
  short8 bb = *(const short8*)&c2wt[ml * 32 + q * 8];
  floatx4 c = {0.f, 0.f, 0.f, 0.f};
  c = __builtin_amdgcn_mfma_f32_16x16x32_bf16(a, bb, c, 0, 0, 0);
  #pragma unroll
  for (int r = 0; r < 4; ++r){
    int gr = r0 + q * 4 + r;
    if (gr < M){
      float v = c[r] * dinv[gr];
      xs2[(size_t)gr * 16 + ml]  = v;
      acc2[(size_t)gr * 16 + ml] = v;
    }
  }
}

// ---------------- degree / dinv --------------------------------------------
__global__ void k_deg_init(float* __restrict__ deg, int Nn){
  int i = blockIdx.x * 256 + threadIdx.x;
  if (i < Nn) deg[i] = 1.0f;   // self-loop
}
__global__ void k_deg_count(const int* __restrict__ ei, float* __restrict__ deg, int E){
  int e = blockIdx.x * 256 + threadIdx.x;
  if (e < E) atomicAdd(&deg[ei[E + e]], 1.0f);
}
__global__ void k_dinv(const float* __restrict__ deg, float* __restrict__ dinv, int Nn){
  int i = blockIdx.x * 256 + threadIdx.x;
  if (i < Nn) dinv[i] = rsqrtf(deg[i]);
}

// ---------------- edge scatter (atomics) -----------------------------------
__global__ void k_scat32(const int* __restrict__ ei, const float* __restrict__ xs,
                         float* __restrict__ acc, int E){
  int gid = blockIdx.x * 256 + threadIdx.x;
  int e = gid >> 5, c = gid & 31;
  if (e >= E) return;
  int s = ei[e], d = ei[E + e];
  atomicAdd(&acc[(size_t)d * 32 + c], xs[(size_t)s * 32 + c]);
}
__global__ void k_scat16(const int* __restrict__ ei, const float* __restrict__ xs,
                         float* __restrict__ acc, int E){
  int gid = blockIdx.x * 256 + threadIdx.x;
  int e = gid >> 4, c = gid & 15;
  if (e >= E) return;
  int s = ei[e], d = ei[E + e];
  atomicAdd(&acc[(size_t)d * 16 + c], xs[(size_t)s * 16 + c]);
}

// ---------------- z = dinv*acc2 + c2b --------------------------------------
__global__ void k_fin2(const float* __restrict__ acc2, const float* __restrict__ c2b,
                       const float* __restrict__ dinv, float* __restrict__ z, int M){
  int gid = blockIdx.x * 256 + threadIdx.x;
  if (gid >= M * 16) return;
  int i = gid >> 4, c = gid & 15;
  z[gid] = dinv[i] * acc2[gid] + c2b[c];
}

// ---------------- edge head MLP --------------------------------------------
__global__ __launch_bounds__(256) void k_edge(const int* __restrict__ ei,
    const int* __restrict__ mask, const float* __restrict__ z,
    const float* __restrict__ lw1, const float* __restrict__ lb1,
    const float* __restrict__ lw2, const float* __restrict__ lb2,
    float* __restrict__ out, int nsel, int E){
  __shared__ float w1s[512], b1s[16], w2s[32], b2s[2];
  int t = threadIdx.x;
  for (int idx = t; idx < 512; idx += 256) w1s[idx] = lw1[idx];
  if (t < 16) b1s[t] = lb1[t];
  if (t < 32) w2s[t] = lw2[t];
  if (t < 2)  b2s[t] = lb2[t];
  __syncthreads();
  int j = blockIdx.x * 256 + t;
  if (j >= nsel) return;
  int m = mask[j];
  int s = ei[m], d = ei[E + m];
  float e[32];
  const float4* zs = (const float4*)(z + (size_t)s * 16);
  const float4* zd = (const float4*)(z + (size_t)d * 16);
  #pragma unroll
  for (int k4 = 0; k4 < 4; ++k4){
    float4 v = zs[k4];
    e[k4 * 4 + 0] = v.x; e[k4 * 4 + 1] = v.y; e[k4 * 4 + 2] = v.z; e[k4 * 4 + 3] = v.w;
  }
  #pragma unroll
  for (int k4 = 0; k4 < 4; ++k4){
    float4 v = zd[k4];
    e[16 + k4 * 4 + 0] = v.x; e[16 + k4 * 4 + 1] = v.y;
    e[16 + k4 * 4 + 2] = v.z; e[16 + k4 * 4 + 3] = v.w;
  }
  float o[16];
  #pragma unroll
  for (int oo = 0; oo < 16; ++oo){
    float acc = b1s[oo];
    #pragma unroll
    for (int ii = 0; ii < 32; ++ii) acc += e[ii] * w1s[ii * 16 + oo];
    o[oo] = eluf(acc);
  }
  float r0 = b2s[0], r1 = b2s[1];
  #pragma unroll
  for (int oo = 0; oo < 16; ++oo){ r0 += o[oo] * w2s[oo * 2]; r1 += o[oo] * w2s[oo * 2 + 1]; }
  out[(size_t)j * 2]     = r0;
  out[(size_t)j * 2 + 1] = r1;
}

extern "C" void kernel_launch(void* const* d_in, const int* in_sizes, int n_in,
                              void* d_out, int out_size, void* d_ws, size_t ws_size,
                              hipStream_t stream){
  const float* x    = (const float*)d_in[0];
  const int*   ei   = (const int*)d_in[1];
  const int*   mask = (const int*)d_in[2];
  const float* ln_g = (const float*)d_in[3];
  const float* ln_b = (const float*)d_in[4];
  const float* w0   = (const float*)d_in[5];
  const float* b0   = (const float*)d_in[6];
  const float* w1   = (const float*)d_in[7];
  const float* b1   = (const float*)d_in[8];
  const float* w2   = (const float*)d_in[9];
  const float* b2   = (const float*)d_in[10];
  const float* c1w  = (const float*)d_in[11];
  const float* c1b  = (const float*)d_in[12];
  const float* c2w  = (const float*)d_in[13];
  const float* c2b  = (const float*)d_in[14];
  const float* lw1  = (const float*)d_in[15];
  const float* lb1  = (const float*)d_in[16];
  const float* lw2  = (const float*)d_in[17];
  const float* lb2  = (const float*)d_in[18];
  float* out = (float*)d_out;

  const int N    = in_sizes[0] / 2048;
  const int E    = in_sizes[1] / 2;
  const int NSEL = in_sizes[2];

  char* ws = (char*)d_ws;
  // region 1 (aliased with h0; tenants written only after gemm1 consumed h0)
  size_t o = 0;
  unsigned short* h2   = (unsigned short*)(ws + o); o += (size_t)N * 256;
  float* xs1  = (float*)(ws + o); o += (size_t)N * 128;
  float* acc1 = (float*)(ws + o); o += (size_t)N * 128;
  float* xs2  = (float*)(ws + o); o += (size_t)N * 64;
  float* acc2 = (float*)(ws + o); o += (size_t)N * 64;
  float* z    = (float*)(ws + o); o += (size_t)N * 64;
  float* deg  = (float*)(ws + o); o += (size_t)N * 4;
  float* dinv = (float*)(ws + o); o += (size_t)N * 4;
  unsigned short* h3 = (unsigned short*)(ws + o);
  unsigned short* h0 = (unsigned short*)(ws + 0);              // alias over region 1
  size_t base2 = (size_t)N * 2048;
  unsigned short* h1   = (unsigned short*)(ws + base2);        o = base2 + (size_t)N * 1024;
  unsigned short* w0t  = (unsigned short*)(ws + o);            o += 1024 * 512 * 2;
  unsigned short* w1t  = (unsigned short*)(ws + o);            o += 512 * 128 * 2;
  unsigned short* w2t  = (unsigned short*)(ws + o);            o += 128 * 64 * 2;
  unsigned short* c1wt = (unsigned short*)(ws + o);            o += 64 * 32 * 2;
  unsigned short* c2wt = (unsigned short*)(ws + o);

  // weight converts/transposes (tiny)
  k_tcvt<<<(1024 * 512 + 255) / 256, 256, 0, stream>>>(w0, w0t, 1024, 512);
  k_tcvt<<<(512 * 128 + 255) / 256, 256, 0, stream>>>(w1, w1t, 512, 128);
  k_tcvt<<<(128 * 64 + 255) / 256, 256, 0, stream>>>(w2, w2t, 128, 64);
  k_tcvt<<<(64 * 32 + 255) / 256, 256, 0, stream>>>(c1w, c1wt, 64, 32);
  k_tcvt<<<(32 * 16 + 255) / 256, 256, 0, stream>>>(c2w, c2wt, 32, 16);

  // maxpool + layernorm -> h0 (bf16)
  k_pool_ln<<<N, 256, 0, stream>>>(x, ln_g, ln_b, h0);

  // GEMM1: h1 = elu(h0 @ w0 + b0)   M x 1024 x 512
  k_gemm<<<dim3((N + 127) / 128, 4), 256, 0, stream>>>(h0, w0t, b0, h1, N, 1024, 512);

  // degrees (region-1 tenants; safe after gemm1 consumed h0)
  k_deg_init<<<(N + 255) / 256, 256, 0, stream>>>(deg, N);
  k_deg_count<<<(E + 255) / 256, 256, 0, stream>>>(ei, deg, E);
  k_dinv<<<(N + 255) / 256, 256, 0, stream>>>(deg, dinv, N);

  // GEMM2: h2 = elu(h1 @ w1 + b1)   M x 512 x 128
  k_gemm<<<dim3((N + 127) / 128, 1), 256, 0, stream>>>(h1, w1t, b1, h2, N, 512, 128);

  // h3 = elu(h2 @ w2 + b2)          M x 128 x 64
  int nwaves = (N + 15) / 16;
  int wblocks = (nwaves + 3) / 4;
  k_h3<<<wblocks, 256, 0, stream>>>(h2, w2t, b2, h3, N);

  // conv1
  k_xs1<<<wblocks, 256, 0, stream>>>(h3, c1wt, dinv, xs1, acc1, N);
  k_scat32<<<((size_t)E * 32 + 255) / 256, 256, 0, stream>>>(ei, xs1, acc1, E);
  k_fin1<<<wblocks, 256, 0, stream>>>(acc1, c1b, c2wt, dinv, xs2, acc2, N);

  // conv2
  k_scat16<<<((size_t)E * 16 + 255) / 256, 256, 0, stream>>>(ei, xs2, acc2, E);
  k_fin2<<<(N * 16 + 255) / 256, 256, 0, stream>>>(acc2, c2b, dinv, z, N);

  // edge head
  k_edge<<<(NSEL + 255) / 256, 256, 0, stream>>>(ei, mask, z, lw1, lb1, lw2, lb2,
                                                 out, NSEL, E);
}

// Round 2
// 974.084 us; speedup vs baseline: 1.1345x; 1.1345x over previous
//
#include <hip/hip_runtime.h>
#include <cstdint>

using short8  = __attribute__((ext_vector_type(8))) short;
using floatx4 = __attribute__((ext_vector_type(4))) float;

__device__ __forceinline__ unsigned short f2bf(float x){
  union { float f; unsigned u; } v; v.f = x;
  unsigned r = v.u + 0x7fffu + ((v.u >> 16) & 1u);
  return (unsigned short)(r >> 16);
}

__device__ __forceinline__ float eluf(float v){ return v > 0.f ? v : expm1f(v); }

__device__ __forceinline__ void ld_g2l16(const void* g, void* l){
  __builtin_amdgcn_global_load_lds(
      (const __attribute__((address_space(1))) void*)g,
      (__attribute__((address_space(3))) void*)l, 16, 0, 0);
}

// ---------------- weight transpose + bf16 convert: Wt[n*K+k] = W[k*N+n] ----
__global__ void k_tcvt(const float* __restrict__ W, unsigned short* __restrict__ Wt,
                       int K, int Ncols){
  int idx = blockIdx.x * 256 + threadIdx.x;
  if (idx >= K * Ncols) return;
  int n = idx / K, k = idx - n * K;
  Wt[idx] = f2bf(W[(size_t)k * Ncols + n]);
}

// ---------------- maxpool(2) + layernorm(1024) -> bf16 ---------------------
__global__ __launch_bounds__(256) void k_pool_ln(const float* __restrict__ x,
    const float* __restrict__ g, const float* __restrict__ b,
    unsigned short* __restrict__ h0){
  const int i = blockIdx.x, t = threadIdx.x;
  const float4* xr = (const float4*)(x + (size_t)i * 2048);
  float4 va = xr[2 * t], vb = xr[2 * t + 1];
  float v0 = fmaxf(va.x, va.y), v1 = fmaxf(va.z, va.w);
  float v2 = fmaxf(vb.x, vb.y), v3 = fmaxf(vb.z, vb.w);
  float s  = v0 + v1 + v2 + v3;
  float s2 = v0*v0 + v1*v1 + v2*v2 + v3*v3;
  #pragma unroll
  for (int off = 32; off > 0; off >>= 1){
    s  += __shfl_down(s, off);
    s2 += __shfl_down(s2, off);
  }
  __shared__ float ps[4], ps2[4];
  int w = t >> 6;
  if ((t & 63) == 0){ ps[w] = s; ps2[w] = s2; }
  __syncthreads();
  float S  = ps[0] + ps[1] + ps[2] + ps[3];
  float S2 = ps2[0] + ps2[1] + ps2[2] + ps2[3];
  float mu   = S * (1.f / 1024.f);
  float var  = S2 * (1.f / 1024.f) - mu * mu;
  float rstd = rsqrtf(var + 1e-5f);
  float4 g4 = ((const float4*)g)[t];
  float4 b4 = ((const float4*)b)[t];
  ushort4 o;
  o.x = f2bf((v0 - mu) * rstd * g4.x + b4.x);
  o.y = f2bf((v1 - mu) * rstd * g4.y + b4.y);
  o.z = f2bf((v2 - mu) * rstd * g4.z + b4.z);
  o.w = f2bf((v3 - mu) * rstd * g4.w + b4.w);
  *(ushort4*)(h0 + (size_t)i * 1024 + t * 4) = o;
}

// ---------------- main MFMA GEMM: C = elu(A@B + bias), bf16 out ------------
__global__ __launch_bounds__(256) void k_gemm(const unsigned short* __restrict__ A,
    const unsigned short* __restrict__ Bt, const float* __restrict__ bias,
    unsigned short* __restrict__ C, int M, int K, int N){
  __shared__ __align__(16) unsigned short lA[128 * 64];
  __shared__ __align__(16) unsigned short lB[128 * 64];
  const int tid  = threadIdx.x;
  const int lane = tid & 63;
  const int w    = tid >> 6;
  const int wm = w >> 1, wn = w & 1;
  const int m0 = blockIdx.x * 128;
  const int n0 = blockIdx.y * 128;
  const int q = lane >> 4, ml = lane & 15;
  floatx4 acc[4][4] = {};
  const int nKB = K >> 6;
  for (int kb = 0; kb < nKB; ++kb){
    #pragma unroll
    for (int i = 0; i < 4; ++i){
      int cpos = (w * 4 + i) * 64 + lane;
      int row  = cpos >> 3;
      int p    = cpos & 7;
      int cc   = p ^ (row & 7);          // XOR swizzle on 16B chunks
      int ar   = m0 + row; ar = ar < M ? ar : M - 1;
      ld_g2l16(A  + (size_t)ar        * K + (kb * 64 + cc * 8), &lA[(w * 4 + i) * 512]);
      ld_g2l16(Bt + (size_t)(n0 + row) * K + (kb * 64 + cc * 8), &lB[(w * 4 + i) * 512]);
    }
    __syncthreads();
    #pragma unroll
    for (int kk = 0; kk < 2; ++kk){
      short8 af[4], bfr[4];
      #pragma unroll
      for (int mi = 0; mi < 4; ++mi){
        int row = wm * 64 + mi * 16 + ml;
        int p   = (kk * 4 + q) ^ (row & 7);
        af[mi] = *(const short8*)&lA[row * 64 + p * 8];
      }
      #pragma unroll
      for (int ni = 0; ni < 4; ++ni){
        int row = wn * 64 + ni * 16 + ml;
        int p   = (kk * 4 + q) ^ (row & 7);
        bfr[ni] = *(const short8*)&lB[row * 64 + p * 8];
      }
      #pragma unroll
      for (int mi = 0; mi < 4; ++mi)
        #pragma unroll
        for (int ni = 0; ni < 4; ++ni)
          acc[mi][ni] = __builtin_amdgcn_mfma_f32_16x16x32_bf16(af[mi], bfr[ni], acc[mi][ni], 0, 0, 0);
    }
    __syncthreads();
  }
  #pragma unroll
  for (int mi = 0; mi < 4; ++mi){
    #pragma unroll
    for (int ni = 0; ni < 4; ++ni){
      int gc = n0 + wn * 64 + ni * 16 + ml;
      float bv = bias[gc];
      #pragma unroll
      for (int r = 0; r < 4; ++r){
        int gr = m0 + wm * 64 + mi * 16 + q * 4 + r;
        if (gr < M){
          float v = acc[mi][ni][r] + bv;
          v = v > 0.f ? v : expm1f(v);
          C[(size_t)gr * N + gc] = f2bf(v);
        }
      }
    }
  }
}

// ------------- h3 = elu(h2 @ w2 + b2): K=128, N=64, 1 wave per 16 rows -----
__global__ __launch_bounds__(256) void k_h3(const unsigned short* __restrict__ h2,
    const unsigned short* __restrict__ w2t, const float* __restrict__ b2,
    unsigned short* __restrict__ h3, int M){
  int gw = (blockIdx.x * 256 + threadIdx.x) >> 6;
  int lane = threadIdx.x & 63;
  int r0 = gw * 16;
  if (r0 >= M) return;
  int ml = lane & 15, q = lane >> 4;
  int ar = r0 + ml; if (ar >= M) ar = M - 1;
  floatx4 acc[4] = {};
  #pragma unroll
  for (int kk = 0; kk < 4; ++kk){
    short8 a = *(const short8*)&h2[(size_t)ar * 128 + kk * 32 + q * 8];
    #pragma unroll
    for (int ni = 0; ni < 4; ++ni){
      short8 bb = *(const short8*)&w2t[(ni * 16 + ml) * 128 + kk * 32 + q * 8];
      acc[ni] = __builtin_amdgcn_mfma_f32_16x16x32_bf16(a, bb, acc[ni], 0, 0, 0);
    }
  }
  #pragma unroll
  for (int ni = 0; ni < 4; ++ni){
    int gc = ni * 16 + ml;
    float bv = b2[gc];
    #pragma unroll
    for (int r = 0; r < 4; ++r){
      int gr = r0 + q * 4 + r;
      if (gr < M) h3[(size_t)gr * 64 + gc] = f2bf(eluf(acc[ni][r] + bv));
    }
  }
}

// ------------- xs1 = (h3 @ c1w) * dinv -------------------------------------
__global__ __launch_bounds__(256) void k_xs1(const unsigned short* __restrict__ h3,
    const unsigned short* __restrict__ c1wt, const float* __restrict__ dinv,
    float* __restrict__ xs1, int M){
  int gw = (blockIdx.x * 256 + threadIdx.x) >> 6;
  int lane = threadIdx.x & 63;
  int r0 = gw * 16;
  if (r0 >= M) return;
  int ml = lane & 15, q = lane >> 4;
  int ar = r0 + ml; if (ar >= M) ar = M - 1;
  floatx4 acc[2] = {};
  #pragma unroll
  for (int kk = 0; kk < 2; ++kk){
    short8 a = *(const short8*)&h3[(size_t)ar * 64 + kk * 32 + q * 8];
    #pragma unroll
    for (int ni = 0; ni < 2; ++ni){
      short8 bb = *(const short8*)&c1wt[(ni * 16 + ml) * 64 + kk * 32 + q * 8];
      acc[ni] = __builtin_amdgcn_mfma_f32_16x16x32_bf16(a, bb, acc[ni], 0, 0, 0);
    }
  }
  #pragma unroll
  for (int ni = 0; ni < 2; ++ni){
    int gc = ni * 16 + ml;
    #pragma unroll
    for (int r = 0; r < 4; ++r){
      int gr = r0 + q * 4 + r;
      if (gr < M) xs1[(size_t)gr * 32 + gc] = acc[ni][r] * dinv[gr];
    }
  }
}

// ------------- h4 = elu(dinv*acc1 + c1b); xs2 = (h4@c2w)*dinv --------------
__global__ __launch_bounds__(256) void k_fin1(const float* __restrict__ acc1,
    const float* __restrict__ c1b, const unsigned short* __restrict__ c2wt,
    const float* __restrict__ dinv, float* __restrict__ xs2, int M){
  int gw = (blockIdx.x * 256 + threadIdx.x) >> 6;
  int lane = threadIdx.x & 63;
  int r0 = gw * 16;
  if (r0 >= M) return;
  int ml = lane & 15, q = lane >> 4;
  int ar = r0 + ml; if (ar >= M) ar = M - 1;
  float dr = dinv[ar];
  short8 a;
  #pragma unroll
  for (int j = 0; j < 8; ++j){
    float v = dr * acc1[(size_t)ar * 32 + q * 8 + j] + c1b[q * 8 + j];
    a[j] = (short)f2bf(eluf(v));
  }
  short8 bb = *(const short8*)&c2wt[ml * 32 + q * 8];
  floatx4 c = {0.f, 0.f, 0.f, 0.f};
  c = __builtin_amdgcn_mfma_f32_16x16x32_bf16(a, bb, c, 0, 0, 0);
  #pragma unroll
  for (int r = 0; r < 4; ++r){
    int gr = r0 + q * 4 + r;
    if (gr < M) xs2[(size_t)gr * 16 + ml] = c[r] * dinv[gr];
  }
}

// ---------------- CSR build ------------------------------------------------
__global__ void k_zero2(int* __restrict__ a, int* __restrict__ b, int Nn){
  int i = blockIdx.x * 256 + threadIdx.x;
  if (i < Nn){ a[i] = 0; b[i] = 0; }
}
__global__ void k_degi(const int* __restrict__ ei, int* __restrict__ deg, int E){
  int e = blockIdx.x * 256 + threadIdx.x;
  if (e < E) atomicAdd(&deg[ei[E + e]], 1);
}
__global__ void k_dinv(const int* __restrict__ deg, float* __restrict__ dinv, int Nn){
  int i = blockIdx.x * 256 + threadIdx.x;
  if (i < Nn) dinv[i] = rsqrtf((float)deg[i] + 1.0f);
}
// block-wise scan step 1: per-block inclusive scan of deg -> ptr (local excl), btot
__global__ __launch_bounds__(256) void k_scan1(const int* __restrict__ deg,
    int* __restrict__ ptr, int* __restrict__ btot, int Nn){
  __shared__ int s[256];
  int b = blockIdx.x, t = threadIdx.x, i = b * 256 + t;
  int v = (i < Nn) ? deg[i] : 0;
  s[t] = v; __syncthreads();
  #pragma unroll
  for (int off = 1; off < 256; off <<= 1){
    int x = (t >= off) ? s[t - off] : 0;
    __syncthreads();
    s[t] += x; __syncthreads();
  }
  if (i < Nn) ptr[i] = s[t] - v;          // exclusive, local
  if (t == 255) btot[b] = s[255];
}
__global__ __launch_bounds__(256) void k_scan2(int* __restrict__ btot, int nb){
  __shared__ int s[256];
  int t = threadIdx.x;
  int v = (t < nb) ? btot[t] : 0;
  s[t] = v; __syncthreads();
  #pragma unroll
  for (int off = 1; off < 256; off <<= 1){
    int x = (t >= off) ? s[t - off] : 0;
    __syncthreads();
    s[t] += x; __syncthreads();
  }
  if (t < nb) btot[t] = s[t] - v;          // exclusive block offsets
}
__global__ void k_scan3(int* __restrict__ ptr, const int* __restrict__ btot, int Nn){
  int i = blockIdx.x * 256 + threadIdx.x;
  if (i < Nn) ptr[i] += btot[blockIdx.x >> 0 ? i >> 8 : 0];  // i>>8 == block of i
}
__global__ void k_fill(const int* __restrict__ ei, const int* __restrict__ ptr,
                       int* __restrict__ cnt, int* __restrict__ csr, int E){
  int e = blockIdx.x * 256 + threadIdx.x;
  if (e >= E) return;
  int d = ei[E + e];
  int pos = ptr[d] + atomicAdd(&cnt[d], 1);
  csr[pos] = ei[e];
}

// ---------------- pull gather: acc[d] = xs[d] + sum_{s in N(d)} xs[s] ------
// C4 float4-columns per row; EPI = 64/C4 edges in flight per wave.
template <int C4, int LOG2C4>
__global__ __launch_bounds__(256) void k_gather(const int* __restrict__ csr,
    const int* __restrict__ ptr, const int* __restrict__ deg,
    const float* __restrict__ xs, float* __restrict__ acc, int M){
  int wid = (blockIdx.x * 256 + threadIdx.x) >> 6;
  if (wid >= M) return;
  int lane = threadIdx.x & 63;
  int g = lane >> LOG2C4;
  int c = lane & (C4 - 1);
  const int EPI = 64 >> LOG2C4;
  int start = ptr[wid], n = deg[wid];
  float4 a = {0.f, 0.f, 0.f, 0.f};
  for (int j = g; j < n; j += EPI){
    int s = csr[start + j];
    float4 v = *(const float4*)&xs[(size_t)s * (C4 * 4) + c * 4];
    a.x += v.x; a.y += v.y; a.z += v.z; a.w += v.w;
  }
  #pragma unroll
  for (int off = C4; off < 64; off <<= 1){
    a.x += __shfl_xor(a.x, off);
    a.y += __shfl_xor(a.y, off);
    a.z += __shfl_xor(a.z, off);
    a.w += __shfl_xor(a.w, off);
  }
  if (g == 0){
    float4 self = *(const float4*)&xs[(size_t)wid * (C4 * 4) + c * 4];
    float4 o = {a.x + self.x, a.y + self.y, a.z + self.z, a.w + self.w};
    *(float4*)&acc[(size_t)wid * (C4 * 4) + c * 4] = o;
  }
}

// ---------------- z = dinv*acc2 + c2b --------------------------------------
__global__ void k_fin2(const float* __restrict__ acc2, const float* __restrict__ c2b,
                       const float* __restrict__ dinv, float* __restrict__ z, int M){
  int gid = blockIdx.x * 256 + threadIdx.x;
  if (gid >= M * 16) return;
  int i = gid >> 4, c = gid & 15;
  z[gid] = dinv[i] * acc2[gid] + c2b[c];
}

// ---------------- edge head MLP --------------------------------------------
__global__ __launch_bounds__(256) void k_edge(const int* __restrict__ ei,
    const int* __restrict__ mask, const float* __restrict__ z,
    const float* __restrict__ lw1, const float* __restrict__ lb1,
    const float* __restrict__ lw2, const float* __restrict__ lb2,
    float* __restrict__ out, int nsel, int E){
  __shared__ float w1s[512], b1s[16], w2s[32], b2s[2];
  int t = threadIdx.x;
  for (int idx = t; idx < 512; idx += 256) w1s[idx] = lw1[idx];
  if (t < 16) b1s[t] = lb1[t];
  if (t < 32) w2s[t] = lw2[t];
  if (t < 2)  b2s[t] = lb2[t];
  __syncthreads();
  int j = blockIdx.x * 256 + t;
  if (j >= nsel) return;
  int m = mask[j];
  int s = ei[m], d = ei[E + m];
  float e[32];
  const float4* zs = (const float4*)(z + (size_t)s * 16);
  const float4* zd = (const float4*)(z + (size_t)d * 16);
  #pragma unroll
  for (int k4 = 0; k4 < 4; ++k4){
    float4 v = zs[k4];
    e[k4 * 4 + 0] = v.x; e[k4 * 4 + 1] = v.y; e[k4 * 4 + 2] = v.z; e[k4 * 4 + 3] = v.w;
  }
  #pragma unroll
  for (int k4 = 0; k4 < 4; ++k4){
    float4 v = zd[k4];
    e[16 + k4 * 4 + 0] = v.x; e[16 + k4 * 4 + 1] = v.y;
    e[16 + k4 * 4 + 2] = v.z; e[16 + k4 * 4 + 3] = v.w;
  }
  float o[16];
  #pragma unroll
  for (int oo = 0; oo < 16; ++oo){
    float acc = b1s[oo];
    #pragma unroll
    for (int ii = 0; ii < 32; ++ii) acc += e[ii] * w1s[ii * 16 + oo];
    o[oo] = eluf(acc);
  }
  float r0 = b2s[0], r1 = b2s[1];
  #pragma unroll
  for (int oo = 0; oo < 16; ++oo){ r0 += o[oo] * w2s[oo * 2]; r1 += o[oo] * w2s[oo * 2 + 1]; }
  out[(size_t)j * 2]     = r0;
  out[(size_t)j * 2 + 1] = r1;
}

extern "C" void kernel_launch(void* const* d_in, const int* in_sizes, int n_in,
                              void* d_out, int out_size, void* d_ws, size_t ws_size,
                              hipStream_t stream){
  const float* x    = (const float*)d_in[0];
  const int*   ei   = (const int*)d_in[1];
  const int*   mask = (const int*)d_in[2];
  const float* ln_g = (const float*)d_in[3];
  const float* ln_b = (const float*)d_in[4];
  const float* w0   = (const float*)d_in[5];
  const float* b0   = (const float*)d_in[6];
  const float* w1   = (const float*)d_in[7];
  const float* b1   = (const float*)d_in[8];
  const float* w2   = (const float*)d_in[9];
  const float* b2   = (const float*)d_in[10];
  const float* c1w  = (const float*)d_in[11];
  const float* c1b  = (const float*)d_in[12];
  const float* c2w  = (const float*)d_in[13];
  const float* c2b  = (const float*)d_in[14];
  const float* lw1  = (const float*)d_in[15];
  const float* lb1  = (const float*)d_in[16];
  const float* lw2  = (const float*)d_in[17];
  const float* lb2  = (const float*)d_in[18];
  float* out = (float*)d_out;

  const int N    = in_sizes[0] / 2048;
  const int E    = in_sizes[1] / 2;
  const int NSEL = in_sizes[2];
  const int NB   = (N + 255) / 256;

  char* ws = (char*)d_ws;
  // region 1 (aliased with h0; tenants written only after gemm1 consumed h0)
  size_t o = 0;
  unsigned short* h2   = (unsigned short*)(ws + o); o += (size_t)N * 256;
  float* xs1  = (float*)(ws + o); o += (size_t)N * 128;
  float* acc1 = (float*)(ws + o); o += (size_t)N * 128;
  float* xs2  = (float*)(ws + o); o += (size_t)N * 64;
  float* acc2 = (float*)(ws + o); o += (size_t)N * 64;
  float* z    = (float*)(ws + o); o += (size_t)N * 64;
  int*   degi = (int*)(ws + o);   o += (size_t)N * 4;
  float* dinv = (float*)(ws + o); o += (size_t)N * 4;
  int*   ptr  = (int*)(ws + o);   o += (size_t)N * 4;
  int*   cnt  = (int*)(ws + o);   o += (size_t)N * 4;
  int*   btot = (int*)(ws + o);   o += 256 * 4;
  int*   csr  = (int*)(ws + o);   o += (size_t)E * 4;
  unsigned short* h3 = (unsigned short*)(ws + o);   o += (size_t)N * 128;
  unsigned short* h0 = (unsigned short*)(ws + 0);   // alias over region 1
  size_t base2 = (size_t)N * 2048;
  unsigned short* h1   = (unsigned short*)(ws + base2);        o = base2 + (size_t)N * 1024;
  unsigned short* w0t  = (unsigned short*)(ws + o);            o += 1024 * 512 * 2;
  unsigned short* w1t  = (unsigned short*)(ws + o);            o += 512 * 128 * 2;
  unsigned short* w2t  = (unsigned short*)(ws + o);            o += 128 * 64 * 2;
  unsigned short* c1wt = (unsigned short*)(ws + o);            o += 64 * 32 * 2;
  unsigned short* c2wt = (unsigned short*)(ws + o);

  // weight converts/transposes (tiny)
  k_tcvt<<<(1024 * 512 + 255) / 256, 256, 0, stream>>>(w0, w0t, 1024, 512);
  k_tcvt<<<(512 * 128 + 255) / 256, 256, 0, stream>>>(w1, w1t, 512, 128);
  k_tcvt<<<(128 * 64 + 255) / 256, 256, 0, stream>>>(w2, w2t, 128, 64);
  k_tcvt<<<(64 * 32 + 255) / 256, 256, 0, stream>>>(c1w, c1wt, 64, 32);
  k_tcvt<<<(32 * 16 + 255) / 256, 256, 0, stream>>>(c2w, c2wt, 32, 16);

  // maxpool + layernorm -> h0 (bf16)
  k_pool_ln<<<N, 256, 0, stream>>>(x, ln_g, ln_b, h0);

  // GEMM1: h1 = elu(h0 @ w0 + b0)   M x 1024 x 512
  k_gemm<<<dim3((N + 127) / 128, 4), 256, 0, stream>>>(h0, w0t, b0, h1, N, 1024, 512);

  // ---- CSR build (region-1 tenants; safe only after gemm1 consumed h0) ----
  k_zero2<<<NB, 256, 0, stream>>>(degi, cnt, N);
  k_degi<<<(E + 255) / 256, 256, 0, stream>>>(ei, degi, E);
  k_dinv<<<NB, 256, 0, stream>>>(degi, dinv, N);
  k_scan1<<<NB, 256, 0, stream>>>(degi, ptr, btot, N);
  k_scan2<<<1, 256, 0, stream>>>(btot, NB);
  k_scan3<<<NB, 256, 0, stream>>>(ptr, btot, N);
  k_fill<<<(E + 255) / 256, 256, 0, stream>>>(ei, ptr, cnt, csr, E);

  // GEMM2: h2 = elu(h1 @ w1 + b1)   M x 512 x 128
  k_gemm<<<dim3((N + 127) / 128, 1), 256, 0, stream>>>(h1, w1t, b1, h2, N, 512, 128);

  // h3 = elu(h2 @ w2 + b2)          M x 128 x 64
  int nwaves = (N + 15) / 16;
  int wblocks = (nwaves + 3) / 4;
  k_h3<<<wblocks, 256, 0, stream>>>(h2, w2t, b2, h3, N);

  // conv1: xs1 = (h3@c1w)*dinv; acc1 = pull-gather; fin1 -> xs2
  k_xs1<<<wblocks, 256, 0, stream>>>(h3, c1wt, dinv, xs1, N);
  k_gather<8, 3><<<(N + 3) / 4, 256, 0, stream>>>(csr, ptr, degi, xs1, acc1, N);
  k_fin1<<<wblocks, 256, 0, stream>>>(acc1, c1b, c2wt, dinv, xs2, N);

  // conv2: acc2 = pull-gather; z = dinv*acc2 + c2b
  k_gather<4, 2><<<(N + 3) / 4, 256, 0, stream>>>(csr, ptr, degi, xs2, acc2, N);
  k_fin2<<<(N * 16 + 255) / 256, 256, 0, stream>>>(acc2, c2b, dinv, z, N);

  // edge head
  k_edge<<<(NSEL + 255) / 256, 256, 0, stream>>>(ei, mask, z, lw1, lb1, lw2, lb2,
                                                 out, NSEL, E);
}